// Round 6
// baseline (74.677 us; speedup 1.0000x reference)
//
#include <hip/hip_runtime.h>

// Shapes (fixed by setup_inputs)
constexpr int N  = 4, C = 64, H = 16, W = 16;
constexpr int NF = 128;
constexpr int D  = C * 9;          // 576
constexpr float EPSF = 1e-5f;

// ---------------------------------------------------------------------------
// Prep: w_t4 float4-layout: elem[(k4*128 + f)*4 + j] = w[f][k4*4 + j]
//       w2f4 float4-layout: elem[((fq*9+ab)*64 + c)*4 + j]
//                           = w[fq*4+j][c*9 + flip(ab)]
// ---------------------------------------------------------------------------
__global__ void k_prep(const float* __restrict__ w,
                       float* __restrict__ w_t4, float* __restrict__ w2f4) {
    const int o = blockIdx.x * 256 + threadIdx.x;
    if (o >= 73728) return;
    const int j = o & 3;
    {
        const int f = (o >> 2) & 127, k4 = o >> 9;
        w_t4[o] = w[f * D + k4 * 4 + j];
    }
    {
        const int c = (o >> 2) & 63, rest = o >> 8;
        const int ab = rest % 9, fq = rest / 9;
        const int a = ab / 3, b = ab % 3;
        w2f4[o] = w[(fq * 4 + j) * D + c * 9 + (2 - a) * 3 + (2 - b)];
    }
}

// ---------------------------------------------------------------------------
// K1: s = conv3x3(x,w) fp64; t = 2r/(2s+eps)
// Grid 256 = (n, oh, ow/4).  Threads 1024 = f(128) x cg(8); cg owns 8 ch.
// x staged fp32 in LDS, padded rows [c][dh][8] -> window = b128+b64 (aligned),
// converted to fp64 once per row, reused across 3 taps x 4 outputs.
// ---------------------------------------------------------------------------
__global__ void __launch_bounds__(1024) k_conv_t(
        const float* __restrict__ x, const float4* __restrict__ w_t4,
        const float* __restrict__ r, float* __restrict__ t_g) {
    __shared__ float  xl[C * 24];          // 6 KB: [c][dh][8] (6 used of 8)
    __shared__ double partd[4 * 7 * 128];  // 28 KB

    const int bid = blockIdx.x;
    const int ow0 = (bid & 3) * 4;
    const int oh  = (bid >> 2) & 15;
    const int n   = bid >> 6;
    const int tid = threadIdx.x;
    const int f   = tid & 127;
    const int cg  = tid >> 7;              // 0..7

    for (int idx = tid; idx < C * 18; idx += 1024) {
        const int c = idx / 18, rem = idx % 18;
        const int dh = rem / 6, dw = rem % 6;
        const int ih = oh - 1 + dh, iw = ow0 - 1 + dw;
        float v = 0.f;
        if (ih >= 0 && ih < H && iw >= 0 && iw < W)
            v = x[((n * C + c) * H + ih) * W + iw];
        xl[c * 24 + dh * 8 + dw] = v;
    }
    __syncthreads();

    double a0 = 0, a1 = 0, a2 = 0, a3 = 0;
    const int c0 = cg * 8;
    const float4* __restrict__ wp = w_t4 + cg * 18 * 128 + f;

#pragma unroll
    for (int half = 0; half < 2; ++half) {
        float wreg[36];
#pragma unroll
        for (int i = 0; i < 9; ++i) {
            const float4 wv = wp[(half * 9 + i) * 128];
            wreg[i * 4 + 0] = wv.x; wreg[i * 4 + 1] = wv.y;
            wreg[i * 4 + 2] = wv.z; wreg[i * 4 + 3] = wv.w;
        }
#pragma unroll
        for (int cl = 0; cl < 4; ++cl) {
            const int c = c0 + half * 4 + cl;
#pragma unroll
            for (int dh = 0; dh < 3; ++dh) {
                const float* rowp = xl + c * 24 + dh * 8;
                const float4 xa = *(const float4*)rowp;       // aligned 16B
                const float2 xb = *(const float2*)(rowp + 4); // aligned 8B
                double xd[6];
                xd[0] = (double)xa.x; xd[1] = (double)xa.y;
                xd[2] = (double)xa.z; xd[3] = (double)xa.w;
                xd[4] = (double)xb.x; xd[5] = (double)xb.y;
#pragma unroll
                for (int b = 0; b < 3; ++b) {
                    const double wd = (double)wreg[cl * 9 + dh * 3 + b];
                    a0 += wd * xd[b];
                    a1 += wd * xd[b + 1];
                    a2 += wd * xd[b + 2];
                    a3 += wd * xd[b + 3];
                }
            }
        }
    }

    if (cg > 0) {
        partd[(0 * 7 + cg - 1) * 128 + f] = a0;
        partd[(1 * 7 + cg - 1) * 128 + f] = a1;
        partd[(2 * 7 + cg - 1) * 128 + f] = a2;
        partd[(3 * 7 + cg - 1) * 128 + f] = a3;
    }
    __syncthreads();
    if (cg == 0) {
#pragma unroll
        for (int g = 0; g < 7; ++g) {
            a0 += partd[(0 * 7 + g) * 128 + f];
            a1 += partd[(1 * 7 + g) * 128 + f];
            a2 += partd[(2 * 7 + g) * 128 + f];
            a3 += partd[(3 * 7 + g) * 128 + f];
        }
        const int base = ((n * NF + f) * H + oh) * W + ow0;
        const float* rp = r + base;
        float* tp = t_g + base;
        tp[0] = (float)((2.0 * (double)rp[0]) / (2.0 * a0 + (double)EPSF));
        tp[1] = (float)((2.0 * (double)rp[1]) / (2.0 * a1 + (double)EPSF));
        tp[2] = (float)((2.0 * (double)rp[2]) / (2.0 * a2 + (double)EPSF));
        tp[3] = (float)((2.0 * (double)rp[3]) / (2.0 * a3 + (double)EPSF));
    }
}

// ---------------------------------------------------------------------------
// K2: out = x * convT3x3(t, w)
// Grid 256 = (n, h, w/4).  Threads 1024 = c(64) x fg(16); fg owns 8 filters.
// t staged in LDS padded [f][a][20] with f-stride 64 -> every window starts
// 16B-aligned: explicit float4+float2 reads.  w-quads preloaded to registers.
// ---------------------------------------------------------------------------
__global__ void __launch_bounds__(1024) k_convT_out(
        const float* __restrict__ x, const float4* __restrict__ w2f4,
        const float* __restrict__ t_g, float* __restrict__ out) {
    __shared__ float tl[NF * 64];          // 32 KB: [f][a][20] (18 used)
    __shared__ float fpart[4 * 15 * 64];   // 15 KB

    const int bid = blockIdx.x;
    const int w0  = (bid & 3) * 4;
    const int h   = (bid >> 2) & 15;
    const int n   = bid >> 6;
    const int tid = threadIdx.x;
    const int c   = tid & 63;
    const int fg  = tid >> 6;              // 0..15

    for (int idx = tid; idx < NF * 54; idx += 1024) {
        const int ff = idx / 54, rem = idx % 54;
        const int a = rem / 18, ww = rem % 18;
        const int oh2 = h - 1 + a, ow = ww - 1;
        float v = 0.f;
        if (oh2 >= 0 && oh2 < H && ow >= 0 && ow < W)
            v = t_g[((n * NF + ff) * H + oh2) * W + ow];
        tl[ff * 64 + a * 20 + ww] = v;
    }
    __syncthreads();

    float b0 = 0, b1 = 0, b2 = 0, b3 = 0;
#pragma unroll
    for (int q = 0; q < 2; ++q) {
        const int fq = fg * 2 + q;
        const float4* __restrict__ wp = w2f4 + fq * 9 * 64 + c;
        float wq[36];
#pragma unroll
        for (int ab = 0; ab < 9; ++ab) {
            const float4 wv = wp[ab * 64];
            wq[ab * 4 + 0] = wv.x; wq[ab * 4 + 1] = wv.y;
            wq[ab * 4 + 2] = wv.z; wq[ab * 4 + 3] = wv.w;
        }
#pragma unroll
        for (int j = 0; j < 4; ++j) {
            const int fbase = (fq * 4 + j) * 64;
#pragma unroll
            for (int a = 0; a < 3; ++a) {
                const float* rowp = tl + fbase + a * 20 + w0;  // 16B-aligned
                const float4 ta = *(const float4*)rowp;
                const float2 tb = *(const float2*)(rowp + 4);
                const float tw[6] = {ta.x, ta.y, ta.z, ta.w, tb.x, tb.y};
#pragma unroll
                for (int b = 0; b < 3; ++b) {
                    const float wv = wq[(a * 3 + b) * 4 + j];
                    b0 += wv * tw[b];
                    b1 += wv * tw[b + 1];
                    b2 += wv * tw[b + 2];
                    b3 += wv * tw[b + 3];
                }
            }
        }
    }

    if (fg > 0) {
        fpart[(0 * 15 + fg - 1) * 64 + c] = b0;
        fpart[(1 * 15 + fg - 1) * 64 + c] = b1;
        fpart[(2 * 15 + fg - 1) * 64 + c] = b2;
        fpart[(3 * 15 + fg - 1) * 64 + c] = b3;
    }
    __syncthreads();
    if (fg == 0) {
#pragma unroll
        for (int g = 0; g < 15; ++g) {
            b0 += fpart[(0 * 15 + g) * 64 + c];
            b1 += fpart[(1 * 15 + g) * 64 + c];
            b2 += fpart[(2 * 15 + g) * 64 + c];
            b3 += fpart[(3 * 15 + g) * 64 + c];
        }
        const int base = ((n * C + c) * H + h) * W + w0;
        out[base + 0] = x[base + 0] * b0;
        out[base + 1] = x[base + 1] * b1;
        out[base + 2] = x[base + 2] * b2;
        out[base + 3] = x[base + 3] * b3;
    }
}

// ---------------------------------------------------------------------------
extern "C" void kernel_launch(void* const* d_in, const int* in_sizes, int n_in,
                              void* d_out, int out_size, void* d_ws, size_t ws_size,
                              hipStream_t stream) {
    const float* x = (const float*)d_in[0];   // (4,64,16,16)
    const float* r = (const float*)d_in[1];   // (4,128,16,16)
    const float* w = (const float*)d_in[2];   // (128,64,3,3)
    float* out = (float*)d_out;               // (4,64,16,16)

    float* ws    = (float*)d_ws;
    float* w_t4  = ws;                        // 73728 floats
    float* w2f4  = w_t4 + 73728;              // 73728 floats (16B-aligned)
    float* t_g   = w2f4 + 73728;              // 131072 floats

    k_prep<<<288, 256, 0, stream>>>(w, w_t4, w2f4);
    k_conv_t<<<256, 1024, 0, stream>>>(x, (const float4*)w_t4, r, t_g);
    k_convT_out<<<256, 1024, 0, stream>>>(x, (const float4*)w2f4, t_g, out);
}

// Round 7
// 71.905 us; speedup vs baseline: 1.0386x; 1.0386x over previous
//
#include <hip/hip_runtime.h>

// Shapes (fixed by setup_inputs)
constexpr int N  = 4, C = 64, H = 16, W = 16;
constexpr int NF = 128;
constexpr int D  = C * 9;          // 576
constexpr float EPSF = 1e-5f;

// ---------------------------------------------------------------------------
// Prep: w_t4 float4-layout: elem[(k4*128 + f)*4 + j] = w[f][k4*4 + j]
//       w2f4 float4-layout: elem[((fq*9+ab)*64 + c)*4 + j]
//                           = w[fq*4+j][c*9 + flip(ab)]
// ---------------------------------------------------------------------------
__global__ void k_prep(const float* __restrict__ w,
                       float* __restrict__ w_t4, float* __restrict__ w2f4) {
    const int o = blockIdx.x * 256 + threadIdx.x;
    if (o >= 73728) return;
    const int j = o & 3;
    {
        const int f = (o >> 2) & 127, k4 = o >> 9;
        w_t4[o] = w[f * D + k4 * 4 + j];
    }
    {
        const int c = (o >> 2) & 63, rest = o >> 8;
        const int ab = rest % 9, fq = rest / 9;
        const int a = ab / 3, b = ab % 3;
        w2f4[o] = w[(fq * 4 + j) * D + c * 9 + (2 - a) * 3 + (2 - b)];
    }
}

// ---------------------------------------------------------------------------
// K1: s = conv3x3(x,w) fp64; t = 2r/(2s+eps)
// Grid 256 = (n4, oh16, owg2, fhalf2): block does 8-wide ow strip x 64 filters
// -> w-slice per block 147 KB (half of full).  Threads 1024 = f(64) x cg(16);
// cg owns 4 channels = 9 w-quads.  x staged fp32 [c][dh][12] (aligned rows).
// Partials partd[cg][o][f] (lane-contiguous, conflict-free).
// ---------------------------------------------------------------------------
__global__ void __launch_bounds__(1024) k_conv_t(
        const float* __restrict__ x, const float4* __restrict__ w_t4,
        const float* __restrict__ r, float* __restrict__ t_g) {
    __shared__ float  xl[C * 36];           // 9.2 KB: [c][dh][12] (10 used)
    __shared__ double partd[16 * 8 * 64];   // 64 KB: [cg][o][f]

    const int bid = blockIdx.x;
    const int fh  = bid & 1;
    const int ow0 = ((bid >> 1) & 1) * 8;
    const int oh  = (bid >> 2) & 15;
    const int n   = bid >> 6;
    const int tid = threadIdx.x;
    const int f   = tid & 63;
    const int cg  = tid >> 6;               // 0..15

    for (int idx = tid; idx < C * 30; idx += 1024) {
        const int c = idx / 30, rem = idx % 30;
        const int dh = rem / 10, dw = rem % 10;
        const int ih = oh - 1 + dh, iw = ow0 - 1 + dw;
        float v = 0.f;
        if (ih >= 0 && ih < H && iw >= 0 && iw < W)
            v = x[((n * C + c) * H + ih) * W + iw];
        xl[c * 36 + dh * 12 + dw] = v;
    }
    __syncthreads();

    const int c0 = cg * 4;
    const float4* __restrict__ wp = w_t4 + (cg * 9) * 128 + fh * 64 + f;

    float wreg[36];
#pragma unroll
    for (int i = 0; i < 9; ++i) {
        const float4 wv = wp[i * 128];
        wreg[i * 4 + 0] = wv.x; wreg[i * 4 + 1] = wv.y;
        wreg[i * 4 + 2] = wv.z; wreg[i * 4 + 3] = wv.w;
    }

    double acc[8];
#pragma unroll
    for (int o = 0; o < 8; ++o) acc[o] = 0.0;

#pragma unroll
    for (int cl = 0; cl < 4; ++cl) {
#pragma unroll
        for (int dh = 0; dh < 3; ++dh) {
            const float* rowp = xl + (c0 + cl) * 36 + dh * 12;
            const float4 xa = *(const float4*)rowp;
            const float4 xb = *(const float4*)(rowp + 4);
            const float2 xc = *(const float2*)(rowp + 8);
            double xd[10];
            xd[0] = (double)xa.x; xd[1] = (double)xa.y;
            xd[2] = (double)xa.z; xd[3] = (double)xa.w;
            xd[4] = (double)xb.x; xd[5] = (double)xb.y;
            xd[6] = (double)xb.z; xd[7] = (double)xb.w;
            xd[8] = (double)xc.x; xd[9] = (double)xc.y;
#pragma unroll
            for (int b = 0; b < 3; ++b) {
                const double wd = (double)wreg[cl * 9 + dh * 3 + b];
#pragma unroll
                for (int o = 0; o < 8; ++o)
                    acc[o] += wd * xd[b + o];
            }
        }
    }

#pragma unroll
    for (int o = 0; o < 8; ++o)
        partd[(cg * 8 + o) * 64 + f] = acc[o];
    __syncthreads();

    if (tid < 512) {
        const int f2 = tid & 63, o = tid >> 6;
        double s = 0.0;
#pragma unroll
        for (int g = 0; g < 16; ++g)
            s += partd[(g * 8 + o) * 64 + f2];
        const int fglob = fh * 64 + f2;
        const int idx = ((n * NF + fglob) * H + oh) * W + ow0 + o;
        t_g[idx] = (float)((2.0 * (double)r[idx]) / (2.0 * s + (double)EPSF));
    }
}

// ---------------------------------------------------------------------------
// K2: out = x * convT3x3(t, w)
// Grid 256 = (n4, h16, wg2, chalf2): block does 8-wide w strip x 32 channels
// -> w2f-slice per block 147 KB (half).  Threads 1024 = c(32) x fg(32);
// fg owns 4 filters (one quad).  t staged [f][a][12] aligned.
// Partials fpart[fg][o][c] (lane-contiguous, 2-way alias only).
// ---------------------------------------------------------------------------
__global__ void __launch_bounds__(1024) k_convT_out(
        const float* __restrict__ x, const float4* __restrict__ w2f4,
        const float* __restrict__ t_g, float* __restrict__ out) {
    __shared__ float tl[NF * 36];           // 18.4 KB: [f][a][12] (10 used)
    __shared__ float fpart[32 * 8 * 32];    // 32.8 KB: [fg][o][c]

    const int bid = blockIdx.x;
    const int ch  = bid & 1;
    const int w0  = ((bid >> 1) & 1) * 8;
    const int h   = (bid >> 2) & 15;
    const int n   = bid >> 6;
    const int tid = threadIdx.x;
    const int c   = tid & 31;
    const int fg  = tid >> 5;               // 0..31

    for (int idx = tid; idx < NF * 30; idx += 1024) {
        const int ff = idx / 30, rem = idx % 30;
        const int a = rem / 10, ww = rem % 10;
        const int oh2 = h - 1 + a, ow = w0 - 1 + ww;
        float v = 0.f;
        if (oh2 >= 0 && oh2 < H && ow >= 0 && ow < W)
            v = t_g[((n * NF + ff) * H + oh2) * W + ow];
        tl[ff * 36 + a * 12 + ww] = v;
    }
    __syncthreads();

    const float4* __restrict__ wp = w2f4 + (fg * 9) * 64 + ch * 32 + c;
    float wq[36];
#pragma unroll
    for (int ab = 0; ab < 9; ++ab) {
        const float4 wv = wp[ab * 64];
        wq[ab * 4 + 0] = wv.x; wq[ab * 4 + 1] = wv.y;
        wq[ab * 4 + 2] = wv.z; wq[ab * 4 + 3] = wv.w;
    }

    float acc[8];
#pragma unroll
    for (int o = 0; o < 8; ++o) acc[o] = 0.f;

#pragma unroll
    for (int j = 0; j < 4; ++j) {
        const int fi = fg * 4 + j;
#pragma unroll
        for (int a = 0; a < 3; ++a) {
            const float* rowp = tl + fi * 36 + a * 12;
            const float4 ta = *(const float4*)rowp;
            const float4 tb = *(const float4*)(rowp + 4);
            const float2 tc = *(const float2*)(rowp + 8);
            const float tw[10] = {ta.x, ta.y, ta.z, ta.w,
                                  tb.x, tb.y, tb.z, tb.w, tc.x, tc.y};
#pragma unroll
            for (int b = 0; b < 3; ++b) {
                const float wv = wq[(a * 3 + b) * 4 + j];
#pragma unroll
                for (int o = 0; o < 8; ++o)
                    acc[o] += wv * tw[b + o];
            }
        }
    }

#pragma unroll
    for (int o = 0; o < 8; ++o)
        fpart[(fg * 8 + o) * 32 + c] = acc[o];
    __syncthreads();

    if (tid < 256) {
        const int c2 = tid & 31, o = tid >> 5;
        float s = 0.f;
#pragma unroll
        for (int g = 0; g < 32; ++g)
            s += fpart[(g * 8 + o) * 32 + c2];
        const int cglob = ch * 32 + c2;
        const int idx = ((n * C + cglob) * H + h) * W + w0 + o;
        out[idx] = x[idx] * s;
    }
}

// ---------------------------------------------------------------------------
extern "C" void kernel_launch(void* const* d_in, const int* in_sizes, int n_in,
                              void* d_out, int out_size, void* d_ws, size_t ws_size,
                              hipStream_t stream) {
    const float* x = (const float*)d_in[0];   // (4,64,16,16)
    const float* r = (const float*)d_in[1];   // (4,128,16,16)
    const float* w = (const float*)d_in[2];   // (128,64,3,3)
    float* out = (float*)d_out;               // (4,64,16,16)

    float* ws    = (float*)d_ws;
    float* w_t4  = ws;                        // 73728 floats
    float* w2f4  = w_t4 + 73728;              // 73728 floats (16B-aligned)
    float* t_g   = w2f4 + 73728;              // 131072 floats

    k_prep<<<288, 256, 0, stream>>>(w, w_t4, w2f4);
    k_conv_t<<<256, 1024, 0, stream>>>(x, (const float4*)w_t4, r, t_g);
    k_convT_out<<<256, 1024, 0, stream>>>(x, (const float4*)w2f4, t_g, out);
}